// Round 3
// baseline (370.867 us; speedup 1.0000x reference)
//
#include <hip/hip_runtime.h>

// ---------------------------------------------------------------------------
// FusedSqueezeExcitation, fp32
//   x : [64, 960, 28, 28]   w1 : [240, 960]   b1 : [240]
//   w2 : [960, 240]         b2 : [960]        out: [64, 960, 28, 28]
//   pooled = mean(x, HW); h = relu(pooled@w1^T+b1);
//   scale = hardsigmoid(h@w2^T+b2); out = scale[n,c] * x
//
// R3: revert apply's nontemporal store -> regular store. Theory: regular
// writes allocate in L3 and drain lazily (kernel retires at L3 speed);
// nt forced synchronous HBM writeout and cost ~60 us. Single-variable round.
// ---------------------------------------------------------------------------

// Stage 1: global average pool. One 64-lane wave per (n,c) row.
// Row = 784 contiguous fp32 = 196 aligned float4 chunks. 4 waves/block.
__global__ void se4_pool(const float* __restrict__ x,
                         float* __restrict__ pooled, int rows) {
    int wid  = (blockIdx.x * 256 + threadIdx.x) >> 6;
    int lane = threadIdx.x & 63;
    if (wid >= rows) return;
    const float4* row = reinterpret_cast<const float4*>(x + (size_t)wid * 784);
    float4 v0 = row[lane];
    float4 v1 = row[lane + 64];
    float4 v2 = row[lane + 128];
    float s = (v0.x + v0.y + v0.z + v0.w)
            + (v1.x + v1.y + v1.z + v1.w)
            + (v2.x + v2.y + v2.z + v2.w);
    if (lane < 4) {                       // 196 = 3*64 + 4 leftover chunks
        float4 v3 = row[lane + 192];
        s += (v3.x + v3.y + v3.z + v3.w);
    }
    #pragma unroll
    for (int off = 32; off > 0; off >>= 1) s += __shfl_down(s, off);
    if (lane == 0) pooled[wid] = s * (1.0f / 784.0f);
}

// Stage 2a: fc1 + ReLU. One wave per (n,s) output: 64*240 = 15360 waves.
// 960-dot = 240 float4 chunks; lane l takes chunks {l, l+64, l+128} and
// (l<48) chunk l+192. Lane-coalesced loads from both pooled row and w1 row.
__global__ void se4_fc1(const float* __restrict__ pooled,
                        const float* __restrict__ w1,
                        const float* __restrict__ b1,
                        float* __restrict__ h) {
    int wid  = (blockIdx.x * 256 + threadIdx.x) >> 6;   // 0..15359
    int lane = threadIdx.x & 63;
    if (wid >= 64 * 240) return;
    int n = wid / 240;
    int s = wid - n * 240;
    const float4* pr = reinterpret_cast<const float4*>(pooled + n * 960);
    const float4* wr = reinterpret_cast<const float4*>(w1 + s * 960);
    float acc = 0.0f;
    #pragma unroll
    for (int k = 0; k < 3; ++k) {
        float4 a = pr[lane + 64 * k];
        float4 b = wr[lane + 64 * k];
        acc += a.x * b.x + a.y * b.y + a.z * b.z + a.w * b.w;
    }
    if (lane < 48) {
        float4 a = pr[lane + 192];
        float4 b = wr[lane + 192];
        acc += a.x * b.x + a.y * b.y + a.z * b.z + a.w * b.w;
    }
    #pragma unroll
    for (int off = 32; off > 0; off >>= 1) acc += __shfl_down(acc, off);
    if (lane == 0) h[wid] = fmaxf(acc + b1[s], 0.0f);
}

// Stage 2b: fc2 + hardsigmoid. One wave per (n,c) output: 64*960 = 61440
// waves. 240-dot = 60 float4 chunks; lanes 0..59 take one chunk each.
__global__ void se4_fc2(const float* __restrict__ h,
                        const float* __restrict__ w2,
                        const float* __restrict__ b2,
                        float* __restrict__ scale) {
    int wid  = (blockIdx.x * 256 + threadIdx.x) >> 6;   // 0..61439
    int lane = threadIdx.x & 63;
    if (wid >= 64 * 960) return;
    int n = wid / 960;
    int c = wid - n * 960;
    float acc = 0.0f;
    if (lane < 60) {
        const float4* hr = reinterpret_cast<const float4*>(h + n * 240);
        const float4* wr = reinterpret_cast<const float4*>(w2 + c * 240);
        float4 a = hr[lane];
        float4 b = wr[lane];
        acc = a.x * b.x + a.y * b.y + a.z * b.z + a.w * b.w;
    }
    #pragma unroll
    for (int off = 32; off > 0; off >>= 1) acc += __shfl_down(acc, off);
    if (lane == 0) {
        float sc = (acc + b2[c] + 3.0f) * (1.0f / 6.0f);
        scale[wid] = fminf(fmaxf(sc, 0.0f), 1.0f);
    }
}

// Stage 3: out = scale[n,c] * x. One thread per float4 chunk; 196 chunks per
// (n,c) row -> row = chunk / 196 (compiler magic-mul). Regular store: writes
// allocate in L3 and drain lazily; x reads are L3-hits (resident from pool).
// Diagnostic clamp: true scale is hardsigmoid(|s|<~0.3) in [0.45,0.55], so
// clamping to [0.25,1] is inert if upstream ran, but turns a poisoned (0xAA)
// workspace into a distinct absmax signature.
__global__ void se4_apply(const float* __restrict__ x,
                          const float* __restrict__ scale,
                          float* __restrict__ out, int nchunks) {
    int g = blockIdx.x * 256 + threadIdx.x;
    if (g >= nchunks) return;
    float sc = scale[g / 196];
    sc = fminf(fmaxf(sc, 0.25f), 1.0f);
    float4 q = reinterpret_cast<const float4*>(x)[g];
    float4 o;
    o.x = q.x * sc; o.y = q.y * sc; o.z = q.z * sc; o.w = q.w * sc;
    reinterpret_cast<float4*>(out)[g] = o;
}

extern "C" __attribute__((visibility("default")))
void kernel_launch(void* const* d_in, const int* in_sizes, int n_in,
                   void* d_out, int out_size, void* d_ws, size_t ws_size,
                   hipStream_t stream) {
    const float* x  = (const float*)d_in[0];
    const float* w1 = (const float*)d_in[1];
    const float* b1 = (const float*)d_in[2];
    const float* w2 = (const float*)d_in[3];
    const float* b2 = (const float*)d_in[4];
    float* out = (float*)d_out;

    const int N = 64, C = 960, Cs = 240;  // H*W = 784
    const int rows = N * C;               // 61440
    float* pooled = (float*)d_ws;         // rows fp32
    float* scale  = pooled + rows;        // rows fp32
    float* h      = scale + rows;         // N*Cs fp32  (total ws ~553 KiB)

    se4_pool<<<(rows + 3) / 4, 256, 0, stream>>>(x, pooled, rows);
    // fc1: 15360 waves -> 3840 blocks of 4 waves
    se4_fc1<<<(N * Cs + 3) / 4, 256, 0, stream>>>(pooled, w1, b1, h);
    // fc2: 61440 waves -> 15360 blocks of 4 waves
    se4_fc2<<<(rows + 3) / 4, 256, 0, stream>>>(h, w2, b2, scale);
    const int nchunks = rows * 196;       // 12,042,240 float4 chunks
    se4_apply<<<(nchunks + 255) / 256, 256, 0, stream>>>(x, scale, out, nchunks);
}

// Round 4
// 365.954 us; speedup vs baseline: 1.0134x; 1.0134x over previous
//
#include <hip/hip_runtime.h>

// ---------------------------------------------------------------------------
// FusedSqueezeExcitation, fp32
//   x : [64, 960, 28, 28]   w1 : [240, 960]   b1 : [240]
//   w2 : [960, 240]         b2 : [960]        out: [64, 960, 28, 28]
//   pooled = mean(x, HW); h = relu(pooled@w1^T+b1);
//   scale = hardsigmoid(h@w2^T+b2); out = scale[n,c] * x
//
// R4: NT stores restored (R2 beat R3 by 9us: non-allocating writes keep x
// L3-resident for apply's reads). Apply rewritten wave-per-row: one
// wave-uniform scale load (no per-thread magic-div), 3 independent float4
// loads issued up front per lane (3x MLP of the 1-chunk/thread form).
// ---------------------------------------------------------------------------

typedef float vfloat4 __attribute__((ext_vector_type(4)));

// Stage 1: global average pool. One 64-lane wave per (n,c) row.
// Row = 784 contiguous fp32 = 196 aligned float4 chunks. 4 waves/block.
__global__ void se4_pool(const float* __restrict__ x,
                         float* __restrict__ pooled, int rows) {
    int wid  = (blockIdx.x * 256 + threadIdx.x) >> 6;
    int lane = threadIdx.x & 63;
    if (wid >= rows) return;
    const float4* row = reinterpret_cast<const float4*>(x + (size_t)wid * 784);
    float4 v0 = row[lane];
    float4 v1 = row[lane + 64];
    float4 v2 = row[lane + 128];
    float s = (v0.x + v0.y + v0.z + v0.w)
            + (v1.x + v1.y + v1.z + v1.w)
            + (v2.x + v2.y + v2.z + v2.w);
    if (lane < 4) {                       // 196 = 3*64 + 4 leftover chunks
        float4 v3 = row[lane + 192];
        s += (v3.x + v3.y + v3.z + v3.w);
    }
    #pragma unroll
    for (int off = 32; off > 0; off >>= 1) s += __shfl_down(s, off);
    if (lane == 0) pooled[wid] = s * (1.0f / 784.0f);
}

// Stage 2a: fc1 + ReLU. One wave per (n,s) output: 64*240 = 15360 waves.
// 960-dot = 240 float4 chunks; lane l takes chunks {l, l+64, l+128} and
// (l<48) chunk l+192. Lane-coalesced loads from both pooled row and w1 row.
__global__ void se4_fc1(const float* __restrict__ pooled,
                        const float* __restrict__ w1,
                        const float* __restrict__ b1,
                        float* __restrict__ h) {
    int wid  = (blockIdx.x * 256 + threadIdx.x) >> 6;   // 0..15359
    int lane = threadIdx.x & 63;
    if (wid >= 64 * 240) return;
    int n = wid / 240;
    int s = wid - n * 240;
    const float4* pr = reinterpret_cast<const float4*>(pooled + n * 960);
    const float4* wr = reinterpret_cast<const float4*>(w1 + s * 960);
    float acc = 0.0f;
    #pragma unroll
    for (int k = 0; k < 3; ++k) {
        float4 a = pr[lane + 64 * k];
        float4 b = wr[lane + 64 * k];
        acc += a.x * b.x + a.y * b.y + a.z * b.z + a.w * b.w;
    }
    if (lane < 48) {
        float4 a = pr[lane + 192];
        float4 b = wr[lane + 192];
        acc += a.x * b.x + a.y * b.y + a.z * b.z + a.w * b.w;
    }
    #pragma unroll
    for (int off = 32; off > 0; off >>= 1) acc += __shfl_down(acc, off);
    if (lane == 0) h[wid] = fmaxf(acc + b1[s], 0.0f);
}

// Stage 2b: fc2 + hardsigmoid. One wave per (n,c) output: 64*960 = 61440
// waves. 240-dot = 60 float4 chunks; lanes 0..59 take one chunk each.
__global__ void se4_fc2(const float* __restrict__ h,
                        const float* __restrict__ w2,
                        const float* __restrict__ b2,
                        float* __restrict__ scale) {
    int wid  = (blockIdx.x * 256 + threadIdx.x) >> 6;   // 0..61439
    int lane = threadIdx.x & 63;
    if (wid >= 64 * 960) return;
    int n = wid / 960;
    int c = wid - n * 960;
    float acc = 0.0f;
    if (lane < 60) {
        const float4* hr = reinterpret_cast<const float4*>(h + n * 240);
        const float4* wr = reinterpret_cast<const float4*>(w2 + c * 240);
        float4 a = hr[lane];
        float4 b = wr[lane];
        acc = a.x * b.x + a.y * b.y + a.z * b.z + a.w * b.w;
    }
    #pragma unroll
    for (int off = 32; off > 0; off >>= 1) acc += __shfl_down(acc, off);
    if (lane == 0) {
        float sc = (acc + b2[c] + 3.0f) * (1.0f / 6.0f);
        scale[wid] = fminf(fmaxf(sc, 0.0f), 1.0f);
    }
}

// Stage 3: out = scale[n,c] * x. One wave per (n,c) row, same shape as pool.
// scale is wave-uniform (one scalar load, no per-thread magic-div); lane l
// handles chunks {l, l+64, l+128} (+tail), loads issued up front for MLP.
// NT stores: out never re-read; non-allocating writes keep x L3-resident so
// this kernel's reads hit L3 (measured: NT beat regular by 9us in R2/R3).
// Diagnostic clamp: true scale is in [0.45,0.55]; clamping to [0.25,1] is
// inert if upstream ran, but turns a poisoned workspace into a distinct
// absmax signature.
__global__ void se4_apply(const float* __restrict__ x,
                          const float* __restrict__ scale,
                          float* __restrict__ out, int rows) {
    int wid  = (blockIdx.x * 256 + threadIdx.x) >> 6;
    int lane = threadIdx.x & 63;
    if (wid >= rows) return;
    float sc = scale[wid];
    sc = fminf(fmaxf(sc, 0.25f), 1.0f);
    const vfloat4* rx = reinterpret_cast<const vfloat4*>(x + (size_t)wid * 784);
    vfloat4* ro = reinterpret_cast<vfloat4*>(out + (size_t)wid * 784);
    vfloat4 v0 = rx[lane];
    vfloat4 v1 = rx[lane + 64];
    vfloat4 v2 = rx[lane + 128];
    __builtin_nontemporal_store(v0 * sc, ro + lane);
    __builtin_nontemporal_store(v1 * sc, ro + lane + 64);
    __builtin_nontemporal_store(v2 * sc, ro + lane + 128);
    if (lane < 4) {
        vfloat4 v3 = rx[lane + 192];
        __builtin_nontemporal_store(v3 * sc, ro + lane + 192);
    }
}

extern "C" __attribute__((visibility("default")))
void kernel_launch(void* const* d_in, const int* in_sizes, int n_in,
                   void* d_out, int out_size, void* d_ws, size_t ws_size,
                   hipStream_t stream) {
    const float* x  = (const float*)d_in[0];
    const float* w1 = (const float*)d_in[1];
    const float* b1 = (const float*)d_in[2];
    const float* w2 = (const float*)d_in[3];
    const float* b2 = (const float*)d_in[4];
    float* out = (float*)d_out;

    const int N = 64, C = 960, Cs = 240;  // H*W = 784
    const int rows = N * C;               // 61440
    float* pooled = (float*)d_ws;         // rows fp32
    float* scale  = pooled + rows;        // rows fp32
    float* h      = scale + rows;         // N*Cs fp32  (total ws ~553 KiB)

    se4_pool<<<(rows + 3) / 4, 256, 0, stream>>>(x, pooled, rows);
    // fc1: 15360 waves -> 3840 blocks of 4 waves
    se4_fc1<<<(N * Cs + 3) / 4, 256, 0, stream>>>(pooled, w1, b1, h);
    // fc2: 61440 waves -> 15360 blocks of 4 waves
    se4_fc2<<<(rows + 3) / 4, 256, 0, stream>>>(h, w2, b2, scale);
    // apply: one wave per row, 4 waves/block
    se4_apply<<<(rows + 3) / 4, 256, 0, stream>>>(x, scale, out, rows);
}

// Round 5
// 356.323 us; speedup vs baseline: 1.0408x; 1.0270x over previous
//
#include <hip/hip_runtime.h>

// ---------------------------------------------------------------------------
// FusedSqueezeExcitation, fp32
//   x : [64, 960, 28, 28]   w1 : [240, 960]   b1 : [240]
//   w2 : [960, 240]         b2 : [960]        out: [64, 960, 28, 28]
//   pooled = mean(x, HW); h = relu(pooled@w1^T+b1);
//   scale = hardsigmoid(h@w2^T+b2); out = scale[n,c] * x
//
// R5: fc2 fused into apply. Each apply wave owns row (n,c); it issues its 3
// x float4 loads FIRST, then computes its own scale (lanes 0-59 do the
// 240-dot of h[n,:].w2[c,:], butterfly reduce, hardsigmoid) while the x
// loads are in flight -> fc2 is hidden under apply's memory latency.
// Removes the fc2 dispatch + launch gap + scale round-trip.
// NT stores kept (R2/R3 A/B: non-allocating writes keep x L3-resident, -9us).
// ---------------------------------------------------------------------------

typedef float vfloat4 __attribute__((ext_vector_type(4)));

// Stage 1: global average pool. One 64-lane wave per (n,c) row.
// Row = 784 contiguous fp32 = 196 aligned float4 chunks. 4 waves/block.
// Regular (allocating) loads: warms L3 with x for the apply pass.
__global__ void se4_pool(const float* __restrict__ x,
                         float* __restrict__ pooled, int rows) {
    int wid  = (blockIdx.x * 256 + threadIdx.x) >> 6;
    int lane = threadIdx.x & 63;
    if (wid >= rows) return;
    const float4* row = reinterpret_cast<const float4*>(x + (size_t)wid * 784);
    float4 v0 = row[lane];
    float4 v1 = row[lane + 64];
    float4 v2 = row[lane + 128];
    float s = (v0.x + v0.y + v0.z + v0.w)
            + (v1.x + v1.y + v1.z + v1.w)
            + (v2.x + v2.y + v2.z + v2.w);
    if (lane < 4) {                       // 196 = 3*64 + 4 leftover chunks
        float4 v3 = row[lane + 192];
        s += (v3.x + v3.y + v3.z + v3.w);
    }
    #pragma unroll
    for (int off = 32; off > 0; off >>= 1) s += __shfl_down(s, off);
    if (lane == 0) pooled[wid] = s * (1.0f / 784.0f);
}

// Stage 2: fc1 + ReLU. One wave per (n,s) output: 64*240 = 15360 waves.
// 960-dot = 240 float4 chunks; lane l takes chunks {l, l+64, l+128} and
// (l<48) chunk l+192. Lane-coalesced loads from both pooled row and w1 row.
__global__ void se4_fc1(const float* __restrict__ pooled,
                        const float* __restrict__ w1,
                        const float* __restrict__ b1,
                        float* __restrict__ h) {
    int wid  = (blockIdx.x * 256 + threadIdx.x) >> 6;   // 0..15359
    int lane = threadIdx.x & 63;
    if (wid >= 64 * 240) return;
    int n = wid / 240;
    int s = wid - n * 240;
    const float4* pr = reinterpret_cast<const float4*>(pooled + n * 960);
    const float4* wr = reinterpret_cast<const float4*>(w1 + s * 960);
    float acc = 0.0f;
    #pragma unroll
    for (int k = 0; k < 3; ++k) {
        float4 a = pr[lane + 64 * k];
        float4 b = wr[lane + 64 * k];
        acc += a.x * b.x + a.y * b.y + a.z * b.z + a.w * b.w;
    }
    if (lane < 48) {
        float4 a = pr[lane + 192];
        float4 b = wr[lane + 192];
        acc += a.x * b.x + a.y * b.y + a.z * b.z + a.w * b.w;
    }
    #pragma unroll
    for (int off = 32; off > 0; off >>= 1) acc += __shfl_down(acc, off);
    if (lane == 0) h[wid] = fmaxf(acc + b1[s], 0.0f);
}

// Stage 3: fused fc2 + hardsigmoid + apply. One wave per (n,c) row.
// x loads issued first (HBM/L3 long pole); the 240-dot (lanes 0-59, one
// float4 chunk each from h[n,:] and w2[c,:], both cache-resident) and the
// 6-step butterfly reduce run while those loads are in flight.
// NT stores: out is never re-read; non-allocating writes keep x L3-resident.
__global__ void se4_fc2_apply(const float* __restrict__ x,
                              const float* __restrict__ h,
                              const float* __restrict__ w2,
                              const float* __restrict__ b2,
                              float* __restrict__ out, int rows) {
    int wid  = (blockIdx.x * 256 + threadIdx.x) >> 6;
    int lane = threadIdx.x & 63;
    if (wid >= rows) return;
    int n = wid / 960;                    // wave-uniform (scalar div)
    int c = wid - n * 960;
    const vfloat4* rx = reinterpret_cast<const vfloat4*>(x + (size_t)wid * 784);
    // Issue the x reads up front.
    vfloat4 v0 = rx[lane];
    vfloat4 v1 = rx[lane + 64];
    vfloat4 v2 = rx[lane + 128];
    vfloat4 v3 = {0.f, 0.f, 0.f, 0.f};
    if (lane < 4) v3 = rx[lane + 192];
    // fc2 dot while x loads are in flight. 240 floats = 60 float4 chunks.
    float acc = 0.0f;
    if (lane < 60) {
        vfloat4 a = reinterpret_cast<const vfloat4*>(h + n * 240)[lane];
        vfloat4 b = reinterpret_cast<const vfloat4*>(w2 + (size_t)c * 240)[lane];
        acc = a.x * b.x + a.y * b.y + a.z * b.z + a.w * b.w;
    }
    #pragma unroll
    for (int off = 1; off < 64; off <<= 1) acc += __shfl_xor(acc, off);
    float sc = (acc + b2[c] + 3.0f) * (1.0f / 6.0f);
    sc = fminf(fmaxf(sc, 0.0f), 1.0f);
    vfloat4* ro = reinterpret_cast<vfloat4*>(out + (size_t)wid * 784);
    __builtin_nontemporal_store(v0 * sc, ro + lane);
    __builtin_nontemporal_store(v1 * sc, ro + lane + 64);
    __builtin_nontemporal_store(v2 * sc, ro + lane + 128);
    if (lane < 4)
        __builtin_nontemporal_store(v3 * sc, ro + lane + 192);
}

extern "C" __attribute__((visibility("default")))
void kernel_launch(void* const* d_in, const int* in_sizes, int n_in,
                   void* d_out, int out_size, void* d_ws, size_t ws_size,
                   hipStream_t stream) {
    const float* x  = (const float*)d_in[0];
    const float* w1 = (const float*)d_in[1];
    const float* b1 = (const float*)d_in[2];
    const float* w2 = (const float*)d_in[3];
    const float* b2 = (const float*)d_in[4];
    float* out = (float*)d_out;

    const int N = 64, C = 960, Cs = 240;  // H*W = 784
    const int rows = N * C;               // 61440
    float* pooled = (float*)d_ws;         // rows fp32
    float* h      = pooled + rows;        // N*Cs fp32 (16B-aligned: 61440*4)

    se4_pool<<<(rows + 3) / 4, 256, 0, stream>>>(x, pooled, rows);
    // fc1: 15360 waves -> 3840 blocks of 4 waves
    se4_fc1<<<(N * Cs + 3) / 4, 256, 0, stream>>>(pooled, w1, b1, h);
    // fused fc2+apply: one wave per row, 4 waves/block
    se4_fc2_apply<<<(rows + 3) / 4, 256, 0, stream>>>(x, h, w2, b2, out, rows);
}